// Round 12
// baseline (39.611 us; speedup 1.0000x reference)
//
#include <hip/hip_runtime.h>
#include <math.h>

#define BB 4
#define SS 4096
#define DK 5
#define NT 256
// (1/sqrt(5)) * log2(e) folded into a' so p = v_exp_f32(score)
#define LAM (0.44721359549995793f * 1.4426950408889634f)

typedef float v2f __attribute__((ext_vector_type(2)));

__device__ __forceinline__ float fast_exp2(float x) {
#if __has_builtin(__builtin_amdgcn_exp2f)
    return __builtin_amdgcn_exp2f(x);
#else
    float r; asm("v_exp_f32 %0, %1" : "=v"(r) : "v"(x)); return r;
#endif
}

// Packed fp32: compiler selects v_pk_fma_f32 on gfx90a+ for <2 x float> fma.
__device__ __forceinline__ v2f pk_fma(v2f a, v2f b, v2f c) {
    return __builtin_elementwise_fma(a, b, c);
}

// ---------------------------------------------------------------------------
// Single fused kernel. V is folded out (out = (Wv·Σp x + bv Σp)/l), bias
// terms folded into a' -> the ONLY per-key data is x_k itself: 48 B per lane
// per 4-key chunk, register-double-buffered straight from global (L1/L2).
// No LDS, no barriers, no separate projection kernel.
//   score_rk = a'_r·x_k,  a'_r = LAM*(M^T x_r + Wk^T bq),  M = Wq^T Wk
//   acc_r = {Σ_past p·x, Σ_past p},  l_r = Σ_all p
//   out_r,d = (Wv[d]·acc_x + bv[d]·acc_p)/l_r
// Every wave owns 2 low + 2 high (mirror) rows: identical work per wave.
// Row pairs are even-aligned so a pair never straddles a 256-key chunk ->
// pair-level wave-uniform gating; per-row fused score->exp->l->acc (R8's
// spill-safe shape).
// ---------------------------------------------------------------------------
__global__ __launch_bounds__(NT) void attn(
    const float* __restrict__ x,
    const float* __restrict__ Wq, const float* __restrict__ bq,
    const float* __restrict__ Wk,
    const float* __restrict__ Wv, const float* __restrict__ bv,
    float* __restrict__ out)
{
    const int tid = threadIdx.x;
    const int sub = tid & 63;
    const int wave = tid >> 6;

    const int b = blockIdx.x >> 8;
    const int i = blockIdx.x & 255;
    const int lo0 = i * 8 + wave * 2;          // rows: lo0, lo0+1, hi0, hi0+1
    const int hi0 = (511 - i) * 8 + wave * 2;
    const int rows[4] = {lo0, lo0 + 1, hi0, hi0 + 1};

    // M = Wq^T Wk (3x3) and u = Wk^T bq (uniform)
    float M00=0,M01=0,M02=0,M10=0,M11=0,M12=0,M20=0,M21=0,M22=0;
    float u0=0,u1=0,u2=0;
#pragma unroll
    for (int d = 0; d < DK; ++d) {
        float q0 = Wq[d*3+0], q1 = Wq[d*3+1], q2 = Wq[d*3+2];
        float k0 = Wk[d*3+0], k1 = Wk[d*3+1], k2 = Wk[d*3+2];
        float bqd = bq[d];
        M00 = fmaf(q0,k0,M00); M01 = fmaf(q0,k1,M01); M02 = fmaf(q0,k2,M02);
        M10 = fmaf(q1,k0,M10); M11 = fmaf(q1,k1,M11); M12 = fmaf(q1,k2,M12);
        M20 = fmaf(q2,k0,M20); M21 = fmaf(q2,k1,M21); M22 = fmaf(q2,k2,M22);
        u0 = fmaf(k0,bqd,u0);  u1 = fmaf(k1,bqd,u1);  u2 = fmaf(k2,bqd,u2);
    }

    const float* xb = x + (size_t)b * SS * 3;

    // per-row a' (broadcast into both packed halves)
    v2f a2[4][3];
#pragma unroll
    for (int r = 0; r < 4; ++r) {
        const float* xr = &xb[(size_t)rows[r] * 3];
        float x0 = xr[0], x1 = xr[1], x2 = xr[2];
        float av0 = LAM * (x0*M00 + x1*M10 + x2*M20 + u0);
        float av1 = LAM * (x0*M01 + x1*M11 + x2*M21 + u1);
        float av2 = LAM * (x0*M02 + x1*M12 + x2*M22 + u2);
        a2[r][0] = (v2f){av0, av0};
        a2[r][1] = (v2f){av1, av1};
        a2[r][2] = (v2f){av2, av2};
    }

    // per-lane epilogue weights (lane sub<5 owns output dim sub)
    float wv0 = 0.f, wv1 = 0.f, wv2 = 0.f, bvl = 0.f;
    if (sub < DK) {
        wv0 = Wv[sub*3+0]; wv1 = Wv[sub*3+1]; wv2 = Wv[sub*3+2]; bvl = bv[sub];
    }

    v2f l2[4];
    v2f acc2[4][4];              // {p*x0, p*x1, p*x2, p} over past keys
#pragma unroll
    for (int r = 0; r < 4; ++r) {
        l2[r] = (v2f){0.f, 0.f};
#pragma unroll
        for (int d = 0; d < 4; ++d) acc2[r][d] = (v2f){0.f, 0.f};
    }

    // register double-buffer: chunk c's 12 floats of x in 3 float4s
    float4 bufA[2], bufB[2], bufC[2];
    {
        const float4* p = (const float4*)(xb + (size_t)(sub * 4) * 3);
        bufA[0] = p[0]; bufB[0] = p[1]; bufC[0] = p[2];
    }

#pragma unroll
    for (int c = 0; c < SS / 256; ++c) {       // 16 chunks of 256 keys
        const int cur = c & 1;
        if (c < SS / 256 - 1) {                // prefetch next chunk
            const float4* p = (const float4*)(xb + (size_t)((c + 1) * 256 + sub * 4) * 3);
            bufA[cur ^ 1] = p[0]; bufB[cur ^ 1] = p[1]; bufC[cur ^ 1] = p[2];
        }
        const float4 A = bufA[cur], B = bufB[cur], C = bufC[cur];
        const int cstart = c * 256;
        const int cend   = cstart + 255;
        const int kbase  = cstart + sub * 4;

        // AoS->packed-SoA register slices (keys 0,1 | 2,3)
#pragma unroll
        for (int h = 0; h < 2; ++h) {
            const int kgh = kbase + h * 2;
            v2f k0, k1, k2;
            if (h == 0) {
                k0 = (v2f){A.x, A.w};
                k1 = (v2f){A.y, B.x};
                k2 = (v2f){A.z, B.y};
            } else {
                k0 = (v2f){B.z, C.y};
                k1 = (v2f){B.w, C.z};
                k2 = (v2f){C.x, C.w};
            }
#pragma unroll
            for (int r = 0; r < 4; ++r) {
                const int row = rows[r];
                v2f sc = pk_fma(a2[r][0], k0,
                         pk_fma(a2[r][1], k1, a2[r][2] * k2));
                v2f p;
                p.x = fast_exp2(sc.x); p.y = fast_exp2(sc.y);
                l2[r] += p;
                if (cend <= row) {              // full accumulate
                    acc2[r][0] = pk_fma(p, k0, acc2[r][0]);
                    acc2[r][1] = pk_fma(p, k1, acc2[r][1]);
                    acc2[r][2] = pk_fma(p, k2, acc2[r][2]);
                    acc2[r][3] += p;
                } else if (cstart <= row) {     // boundary: masked
                    v2f pm;
                    pm.x = (kgh + 0 <= row) ? p.x : 0.f;
                    pm.y = (kgh + 1 <= row) ? p.y : 0.f;
                    acc2[r][0] = pk_fma(pm, k0, acc2[r][0]);
                    acc2[r][1] = pk_fma(pm, k1, acc2[r][1]);
                    acc2[r][2] = pk_fma(pm, k2, acc2[r][2]);
                    acc2[r][3] += pm;
                }
                // else: future-only for this row -> denominator only
            }
        }
    }

    // fold packed halves, butterfly-reduce 5 values across 64 lanes, project
#pragma unroll
    for (int r = 0; r < 4; ++r) {
        float lr = l2[r].x + l2[r].y;
        float A0 = acc2[r][0].x + acc2[r][0].y;
        float A1 = acc2[r][1].x + acc2[r][1].y;
        float A2 = acc2[r][2].x + acc2[r][2].y;
        float PS = acc2[r][3].x + acc2[r][3].y;
#pragma unroll
        for (int off = 32; off >= 1; off >>= 1) {
            lr += __shfl_xor(lr, off);
            A0 += __shfl_xor(A0, off);
            A1 += __shfl_xor(A1, off);
            A2 += __shfl_xor(A2, off);
            PS += __shfl_xor(PS, off);
        }
        if (sub < DK) {
            float num = fmaf(wv0, A0, fmaf(wv1, A1, fmaf(wv2, A2, bvl * PS)));
            out[((size_t)b * SS + rows[r]) * DK + sub] = num / lr;
        }
    }
}

extern "C" void kernel_launch(void* const* d_in, const int* in_sizes, int n_in,
                              void* d_out, int out_size, void* d_ws, size_t ws_size,
                              hipStream_t stream) {
    const float* x  = (const float*)d_in[0];
    const float* Wq = (const float*)d_in[1];
    const float* bq = (const float*)d_in[2];
    const float* Wk = (const float*)d_in[3];
    const float* Wv = (const float*)d_in[5];
    const float* bv = (const float*)d_in[6];
    float* outp = (float*)d_out;

    attn<<<BB * (SS / 16), NT, 0, stream>>>(x, Wq, bq, Wk, Wv, bv, outp);
}